// Round 21
// baseline (31.917 us; speedup 1.0000x reference)
//
#include <hip/hip_runtime.h>

// RFCN PSROI — FINAL FALSIFICATION: float4 (16 B/lane, 1 KB/wave-load) proj.
//   out[b,n,g] = B'[g] + (1/denom) * sum_{bin} Z[b,g,h,w]
//   Z = einsum('bchw,gc->bghw', features, W'),  W'[g,c] = sum_k w[g*9+k, c]
// Hypothesis: proj's invariant ~18us across 7 variants is bound by <=8 B/lane
// load granularity; m13's 6.3 TB/s uses 16 B/lane. This is the only untested
// mechanism (r18's 16B DMA was confounded by serial stage->wait->compute).
// (1) fold weights -> Wred/Bred
// (2) proj: grid (16 tiles x 8 chunks x B) = 256 blocks (1/CU), 512 thr;
//     thread owns 4 contiguous px (float4); wave sl owns 16 channels;
//     16 x global_load_dwordx4 per thread, interleaved with FMAs;
//     paired-wave float4 LDS reduce (102.4 KB).
// (3) ig: per (b,g): 8-chunk sum + 2D prefix scan + proposal gather.
// Dead ends (do not revisit): cross-block sync (r10 261us, r12 174us),
// atomics reduce (r19 160us), in-block wfold (r13/r15), serial DMA (r18).

#define HW 4096      // 64*64
#define NG 25        // 21 cls + 4 reg groups
#define CIN 1024
#define B 2
#define NPROP 1000
#define NCH 8                 // channel chunks in workspace
#define CK (CIN / NCH)        // 128 channels per chunk
#define NSL 8                 // waves per proj block
#define CS (CK / NSL)         // 16 channels per wave
#define MHW (B * NG * HW)     // 204800: one partial chunk
#define PX 256                // pixels per proj block (64 lanes x 4)

// ---------------- Kernel 1: fold weights over the K*K=9 channel groups ----
__global__ void rfcn_wfold(const float* __restrict__ w_cls,
                           const float* __restrict__ b_cls,
                           const float* __restrict__ w_reg,
                           const float* __restrict__ b_reg,
                           float* __restrict__ Wred,   // [25][1024]
                           float* __restrict__ Bred) { // [25]
    int i = blockIdx.x * 256 + threadIdx.x;
    if (i < NG * CIN) {
        int g = i >> 10, c = i & (CIN - 1);
        float s = 0.f;
        if (g < 21) {
            #pragma unroll
            for (int k = 0; k < 9; ++k) s += w_cls[(size_t)(g * 9 + k) * CIN + c];
        } else {
            int gr = g - 21;
            #pragma unroll
            for (int k = 0; k < 9; ++k) s += w_reg[(size_t)(gr * 9 + k) * CIN + c];
        }
        Wred[i] = s;
    } else if (i < NG * CIN + NG) {
        int g = i - NG * CIN;
        float s = 0.f;
        if (g < 21) {
            #pragma unroll
            for (int k = 0; k < 9; ++k) s += b_cls[g * 9 + k];
        } else {
            #pragma unroll
            for (int k = 0; k < 9; ++k) s += b_reg[(g - 21) * 9 + k];
        }
        Bred[g] = s;
    }
}

// ---------------- Kernel 2: projection, float4 streaming ------------------
// grid = (16 px tiles, 8 chunks, B) = 256 blocks, block = 512 (8 waves).
// Wave sl owns channels [chunk*128 + sl*16, +16); lane owns px quad
// [pix0 + 4*lane, +4). Loads: global_load_dwordx4, 1 KB/wave contiguous.
// part layout: [chunk][b][g][4096]
__global__ __launch_bounds__(512)
void rfcn_proj(const float* __restrict__ feats,
               const float* __restrict__ Wred,
               float* __restrict__ part) {
    const int t = threadIdx.x;
    const int lane = t & 63;
    // wave id via readfirstlane -> SGPR, keeps weight loads scalar (s_load)
    const int sl = __builtin_amdgcn_readfirstlane(t >> 6);   // 0..7
    const int pix0 = blockIdx.x * PX;
    const int chunk = blockIdx.y;
    const int b = blockIdx.z;
    const int c0 = chunk * CK + sl * CS;       // wave's first channel

    const float4* __restrict__ f4 =
        (const float4*)(feats + ((size_t)b * CIN + c0) * HW + pix0) + lane;
    const float* __restrict__ wgt = Wred + c0; // scalar-indexed -> s_load

    float4 acc[NG];
    #pragma unroll
    for (int g = 0; g < NG; ++g) acc[g] = make_float4(0.f, 0.f, 0.f, 0.f);

    // two batches of 8 independent dwordx4 loads, FMAs between
    #pragma unroll
    for (int cc = 0; cc < CS; cc += 8) {
        float4 fv[8];
        #pragma unroll
        for (int j = 0; j < 8; ++j)
            fv[j] = f4[(size_t)(cc + j) * (HW / 4)];
        #pragma unroll
        for (int j = 0; j < 8; ++j)
            #pragma unroll
            for (int g = 0; g < NG; ++g) {
                const float w = wgt[g * CIN + cc + j];
                acc[g].x += fv[j].x * w;
                acc[g].y += fv[j].y * w;
                acc[g].z += fv[j].z * w;
                acc[g].w += fv[j].w * w;
            }
    }

    // paired-wave float4 LDS reduction: red4[4][25][64] = 102.4 KB
    __shared__ float4 red4[(NSL / 2) * NG * 64];
    if (sl >= 4) {
        #pragma unroll
        for (int g = 0; g < NG; ++g) red4[((sl - 4) * NG + g) * 64 + lane] = acc[g];
    }
    __syncthreads();
    if (sl < 4) {
        #pragma unroll
        for (int g = 0; g < NG; ++g) {
            float4 r = red4[(sl * NG + g) * 64 + lane];
            r.x += acc[g].x; r.y += acc[g].y; r.z += acc[g].z; r.w += acc[g].w;
            red4[(sl * NG + g) * 64 + lane] = r;
        }
    }
    __syncthreads();

    // 4->1 sum + coalesced float4 store (1 KB/wave)
    float4* __restrict__ o4 =
        (float4*)(part + ((size_t)(chunk * B + b) * NG) * HW + pix0);
    for (int idx = t; idx < NG * 64; idx += 512) {
        const int g = idx >> 6, l = idx & 63;
        float4 s = red4[(0 * NG + g) * 64 + l];
        #pragma unroll
        for (int ss = 1; ss < 4; ++ss) {
            const float4 r = red4[(ss * NG + g) * 64 + l];
            s.x += r.x; s.y += r.y; s.z += r.z; s.w += r.w;
        }
        o4[(size_t)g * (HW / 4) + l] = s;
    }
}

// ---------------- Kernel 3: 8-chunk sum + 2D prefix sum + gather -----------
// grid = 50 (m = b*25+g), block = 1024 (16 waves) — each wave scans 4 rows
// then 4 cols (independent 6-deep shfl chains).
// LDS 64x65: pad kills row-phase conflicts; col stride 65 == 1 (mod 32).
__global__ __launch_bounds__(1024)
void rfcn_integral_gather(const float* __restrict__ part,
                          const int* __restrict__ props,
                          const float* __restrict__ Bred,
                          float* __restrict__ out) {
    const int m = blockIdx.x;        // b*25 + g
    const int t = threadIdx.x;
    const int lane = t & 63;
    const int wave = t >> 6;         // 0..15
    const int b = m / NG;
    const int g = m - b * NG;        // block-uniform
    __shared__ float tile[64 * 65];

    // phase 1: sum the 8 partial chunks (32 independent coalesced loads)
    #pragma unroll
    for (int i = 0; i < 4; ++i) {
        const int idx = i * 1024 + t;
        float v[NCH];
        #pragma unroll
        for (int ch = 0; ch < NCH; ++ch)
            v[ch] = part[(size_t)(ch * (B * NG) + m) * HW + idx];
        #pragma unroll
        for (int off = NCH / 2; off >= 1; off >>= 1)
            #pragma unroll
            for (int j = 0; j < off; ++j) v[j] += v[j + off];
        tile[(idx >> 6) * 65 + (idx & 63)] = v[0];
    }
    __syncthreads();

    // phase 2: row scans — wave w owns rows [w*4, w*4+4), lane = column
    #pragma unroll
    for (int i = 0; i < 4; ++i) {
        const int row = wave * 4 + i;
        float v = tile[row * 65 + lane];
        #pragma unroll
        for (int d = 1; d < 64; d <<= 1) {
            float u = __shfl_up(v, (unsigned)d, 64);
            if (lane >= d) v += u;
        }
        tile[row * 65 + lane] = v;
    }
    __syncthreads();

    // phase 3: column scans — wave w owns cols [w*4, w*4+4), lane = row
    #pragma unroll
    for (int i = 0; i < 4; ++i) {
        const int col = wave * 4 + i;
        float v = tile[lane * 65 + col];
        #pragma unroll
        for (int d = 1; d < 64; d <<= 1) {
            float u = __shfl_up(v, (unsigned)d, 64);
            if (lane >= d) v += u;
        }
        tile[lane * 65 + col] = v;
    }
    __syncthreads();

    // phase 4: per-proposal 4-corner lookups straight from LDS
    const float bias = Bred[g];
    const int n = t;
    if (n < NPROP) {
        const int4 pr = ((const int4*)props)[b * NPROP + n];
        const int x1 = pr.x >> 5;            // floor(px/32), px >= 0
        const int y1 = pr.y >> 5;
        const int x2 = (pr.z + 31) >> 5;     // ceil
        const int y2 = (pr.w + 31) >> 5;
        const int wb = (x2 - x1 + 2) / 3;    // ceil((x2-x1)/3), >= 1
        const int hb = (y2 - y1 + 2) / 3;
        const int c2 = x1 + wb - 1;          // inclusive corner, <= 63
        const int r2 = y1 + hb - 1;

        float s = tile[r2 * 65 + c2];
        if (x1 > 0)           s -= tile[r2 * 65 + (x1 - 1)];
        if (y1 > 0)           s -= tile[(y1 - 1) * 65 + c2];
        if (x1 > 0 && y1 > 0) s += tile[(y1 - 1) * 65 + (x1 - 1)];
        const float v = bias + s / (float)(hb * wb);
        if (g < 21)  // block-uniform branch
            out[(size_t)(b * NPROP + n) * 21 + g] = v;
        else
            out[(size_t)(B * NPROP * 21) + (size_t)(b * NPROP + n) * 4 + (g - 21)] = v;
    }
}

extern "C" void kernel_launch(void* const* d_in, const int* in_sizes, int n_in,
                              void* d_out, int out_size, void* d_ws, size_t ws_size,
                              hipStream_t stream) {
    const float* feats = (const float*)d_in[0];  // [2,1024,64,64]
    const float* w_cls = (const float*)d_in[1];  // [189,1024]
    const float* b_cls = (const float*)d_in[2];  // [189]
    const float* w_reg = (const float*)d_in[3];  // [36,1024]
    const float* b_reg = (const float*)d_in[4];  // [36]
    const int*   props = (const int*)d_in[5];    // [2,1000,4]
    float* out = (float*)d_out;
    float* ws  = (float*)d_ws;

    // workspace layout (floats): ~6.7 MB total
    float* Wred = ws;                        // 25600
    float* Bred = ws + 25600;                // 25 (next region 128B-aligned)
    float* part = ws + 25632;                // 8 * 204800

    rfcn_wfold<<<(NG * CIN + NG + 255) / 256, 256, 0, stream>>>(
        w_cls, b_cls, w_reg, b_reg, Wred, Bred);
    rfcn_proj<<<dim3(HW / PX, NCH, B), 512, 0, stream>>>(feats, Wred, part);
    rfcn_integral_gather<<<B * NG, 1024, 0, stream>>>(part, props, Bred, out);
}

// Round 22
// 27.607 us; speedup vs baseline: 1.1561x; 1.1561x over previous
//
#include <hip/hip_runtime.h>

// RFCN PSROI — CHAMPION (round-14 verbatim; 27.66/27.72us, twice-verified):
//   out[b,n,g] = B'[g] + (1/denom) * sum_{bin} Z[b,g,h,w]
//   Z = einsum('bchw,gc->bghw', features, W'),  W'[g,c] = sum_k w[g*9+k, c]
// (1) fold weights -> Wred/Bred, (2) project -> 25-ch partial maps
//     (4 channel chunks; 512 blocks x 512 thr = 2 blocks/CU; paired-wave
//     LDS reduce), (3) per (b,g): 4-chunk sum + 2D prefix scan + gather.
//
// Session ledger (r16 diagnostic + 8 proj variants): proj's 33.5MB channel-
// strided read runs at an implementation-invariant ~18us (~7 GB/s/CU) across
// scalar/float2/float4/DMA/LDS-weight/occupancy variants. wfold 1.7us, ig
// 2.9us, ~1.7us/node overhead -> 27.7us total = structural floor.
// Dead ends (do not revisit): cross-block sync (r10 261us, r12 174us),
// atomics reduce (r19 160us), in-block wfold (r13/r15 +3.5us), serial DMA
// (r18 +3us), float4 proj + 8-chunk ig (r21 +4.2us).

#define HW 4096      // 64*64
#define NG 25        // 21 cls + 4 reg groups
#define CIN 1024
#define B 2
#define NPROP 1000
#define NCH 4                 // channel chunks in workspace
#define CK (CIN / NCH)        // 256 channels per chunk
#define NSL 8                 // waves per proj block
#define CS (CK / NSL)         // 32 channels per wave
#define MHW (B * NG * HW)     // 204800: one partial chunk

// ---------------- Kernel 1: fold weights over the K*K=9 channel groups ----
__global__ void rfcn_wfold(const float* __restrict__ w_cls,
                           const float* __restrict__ b_cls,
                           const float* __restrict__ w_reg,
                           const float* __restrict__ b_reg,
                           float* __restrict__ Wred,   // [25][1024]
                           float* __restrict__ Bred) { // [25]
    int i = blockIdx.x * 256 + threadIdx.x;
    if (i < NG * CIN) {
        int g = i >> 10, c = i & (CIN - 1);
        float s = 0.f;
        if (g < 21) {
            #pragma unroll
            for (int k = 0; k < 9; ++k) s += w_cls[(size_t)(g * 9 + k) * CIN + c];
        } else {
            int gr = g - 21;
            #pragma unroll
            for (int k = 0; k < 9; ++k) s += w_reg[(size_t)(gr * 9 + k) * CIN + c];
        }
        Wred[i] = s;
    } else if (i < NG * CIN + NG) {
        int g = i - NG * CIN;
        float s = 0.f;
        if (g < 21) {
            #pragma unroll
            for (int k = 0; k < 9; ++k) s += b_cls[g * 9 + k];
        } else {
            #pragma unroll
            for (int k = 0; k < 9; ++k) s += b_reg[(g - 21) * 9 + k];
        }
        Bred[g] = s;
    }
}

// ---------------- Kernel 2: projection  Z_partial = W' x F ----------------
// grid = (64 px tiles, 4 chunks, B) = 512 blocks, block = 512 (8 waves)
// -> 2 independent blocks/CU (LDS 25.6 KB). Wave sl owns channels
// [chunk*256 + sl*32, +32); batches of 16 independent loads in flight.
// part layout: [chunk][b][g][4096]
__global__ __launch_bounds__(512)
void rfcn_proj(const float* __restrict__ feats,
               const float* __restrict__ Wred,
               float* __restrict__ part) {
    const int t = threadIdx.x;
    const int p = t & 63;                      // pixel within tile
    // wave id via readfirstlane -> SGPR, keeps weight loads scalar (s_load)
    const int sl = __builtin_amdgcn_readfirstlane(t >> 6);   // 0..7
    const int pix0 = blockIdx.x * 64;
    const int chunk = blockIdx.y;
    const int b = blockIdx.z;
    const int c0 = chunk * CK + sl * CS;       // wave's first channel

    const float* __restrict__ f = feats + ((size_t)b * CIN + c0) * HW + pix0 + p;
    const float* __restrict__ wgt = Wred + c0; // scalar-indexed -> s_load

    float acc[NG];
    #pragma unroll
    for (int g = 0; g < NG; ++g) acc[g] = 0.f;

    // batches of 16 independent loads in flight, then FMA
    #pragma unroll
    for (int cc = 0; cc < CS; cc += 16) {
        float fv[16];
        #pragma unroll
        for (int j = 0; j < 16; ++j) fv[j] = f[(size_t)(cc + j) * HW];
        #pragma unroll
        for (int j = 0; j < 16; ++j)
            #pragma unroll
            for (int g = 0; g < NG; ++g)
                acc[g] += fv[j] * wgt[g * CIN + cc + j];
    }

    // paired-wave LDS reduction: red[4][25][64] = 25.6 KB
    __shared__ float red[(NSL / 2) * NG * 64];
    if (sl >= 4) {
        #pragma unroll
        for (int g = 0; g < NG; ++g) red[((sl - 4) * NG + g) * 64 + p] = acc[g];
    }
    __syncthreads();
    if (sl < 4) {
        #pragma unroll
        for (int g = 0; g < NG; ++g) red[(sl * NG + g) * 64 + p] += acc[g];
    }
    __syncthreads();

    // 4->1 sum + coalesced store
    float* __restrict__ o = part + ((size_t)(chunk * B + b) * NG) * HW + pix0;
    for (int idx = t; idx < NG * 64; idx += 512) {
        const int g = idx >> 6, pp = idx & 63;
        float s = red[(0 * NG + g) * 64 + pp] + red[(1 * NG + g) * 64 + pp]
                + red[(2 * NG + g) * 64 + pp] + red[(3 * NG + g) * 64 + pp];
        o[(size_t)g * HW + pp] = s;
    }
}

// ---------------- Kernel 3: 4-chunk sum + 2D prefix sum + gather -----------
// grid = 50 (m = b*25+g), block = 1024 (16 waves) — each wave scans 4 rows
// then 4 cols (independent 6-deep shfl chains).
// LDS 64x65: pad kills row-phase conflicts; col stride 65 == 1 (mod 32).
__global__ __launch_bounds__(1024)
void rfcn_integral_gather(const float* __restrict__ part,
                          const int* __restrict__ props,
                          const float* __restrict__ Bred,
                          float* __restrict__ out) {
    const int m = blockIdx.x;        // b*25 + g
    const int t = threadIdx.x;
    const int lane = t & 63;
    const int wave = t >> 6;         // 0..15
    const int b = m / NG;
    const int g = m - b * NG;        // block-uniform
    __shared__ float tile[64 * 65];

    // phase 1: sum the 4 partial chunks (16 independent coalesced loads)
    #pragma unroll
    for (int i = 0; i < 4; ++i) {
        const int idx = i * 1024 + t;
        float v[NCH];
        #pragma unroll
        for (int ch = 0; ch < NCH; ++ch)
            v[ch] = part[(size_t)(ch * (B * NG) + m) * HW + idx];
        #pragma unroll
        for (int off = NCH / 2; off >= 1; off >>= 1)
            #pragma unroll
            for (int j = 0; j < off; ++j) v[j] += v[j + off];
        tile[(idx >> 6) * 65 + (idx & 63)] = v[0];
    }
    __syncthreads();

    // phase 2: row scans — wave w owns rows [w*4, w*4+4), lane = column
    #pragma unroll
    for (int i = 0; i < 4; ++i) {
        const int row = wave * 4 + i;
        float v = tile[row * 65 + lane];
        #pragma unroll
        for (int d = 1; d < 64; d <<= 1) {
            float u = __shfl_up(v, (unsigned)d, 64);
            if (lane >= d) v += u;
        }
        tile[row * 65 + lane] = v;
    }
    __syncthreads();

    // phase 3: column scans — wave w owns cols [w*4, w*4+4), lane = row
    #pragma unroll
    for (int i = 0; i < 4; ++i) {
        const int col = wave * 4 + i;
        float v = tile[lane * 65 + col];
        #pragma unroll
        for (int d = 1; d < 64; d <<= 1) {
            float u = __shfl_up(v, (unsigned)d, 64);
            if (lane >= d) v += u;
        }
        tile[lane * 65 + col] = v;
    }
    __syncthreads();

    // phase 4: per-proposal 4-corner lookups straight from LDS
    const float bias = Bred[g];
    const int n = t;
    if (n < NPROP) {
        const int4 pr = ((const int4*)props)[b * NPROP + n];
        const int x1 = pr.x >> 5;            // floor(px/32), px >= 0
        const int y1 = pr.y >> 5;
        const int x2 = (pr.z + 31) >> 5;     // ceil
        const int y2 = (pr.w + 31) >> 5;
        const int wb = (x2 - x1 + 2) / 3;    // ceil((x2-x1)/3), >= 1
        const int hb = (y2 - y1 + 2) / 3;
        const int c2 = x1 + wb - 1;          // inclusive corner, <= 63
        const int r2 = y1 + hb - 1;

        float s = tile[r2 * 65 + c2];
        if (x1 > 0)           s -= tile[r2 * 65 + (x1 - 1)];
        if (y1 > 0)           s -= tile[(y1 - 1) * 65 + c2];
        if (x1 > 0 && y1 > 0) s += tile[(y1 - 1) * 65 + (x1 - 1)];
        const float v = bias + s / (float)(hb * wb);
        if (g < 21)  // block-uniform branch
            out[(size_t)(b * NPROP + n) * 21 + g] = v;
        else
            out[(size_t)(B * NPROP * 21) + (size_t)(b * NPROP + n) * 4 + (g - 21)] = v;
    }
}

extern "C" void kernel_launch(void* const* d_in, const int* in_sizes, int n_in,
                              void* d_out, int out_size, void* d_ws, size_t ws_size,
                              hipStream_t stream) {
    const float* feats = (const float*)d_in[0];  // [2,1024,64,64]
    const float* w_cls = (const float*)d_in[1];  // [189,1024]
    const float* b_cls = (const float*)d_in[2];  // [189]
    const float* w_reg = (const float*)d_in[3];  // [36,1024]
    const float* b_reg = (const float*)d_in[4];  // [36]
    const int*   props = (const int*)d_in[5];    // [2,1000,4]
    float* out = (float*)d_out;
    float* ws  = (float*)d_ws;

    // workspace layout (floats): ~3.4 MB total
    float* Wred = ws;                        // 25600
    float* Bred = ws + 25600;                // 25 (next region 128B-aligned)
    float* part = ws + 25632;                // 4 * 204800

    rfcn_wfold<<<(NG * CIN + NG + 255) / 256, 256, 0, stream>>>(
        w_cls, b_cls, w_reg, b_reg, Wred, Bred);
    rfcn_proj<<<dim3(HW / 64, NCH, B), 512, 0, stream>>>(feats, Wred, part);
    rfcn_integral_gather<<<B * NG, 1024, 0, stream>>>(part, props, Bred, out);
}